// Round 11
// baseline (471.111 us; speedup 1.0000x reference)
//
#include <hip/hip_runtime.h>
#include <hip/hip_fp16.h>

// 2-layer GCN: out = gcn(relu(gcn(x,W1,b1,e0)), W2, b2, e1)
// R1-R10 lessons: no device-scope atomics anywhere (R2/R10); write-amp 1.0
//   via LDS chunk-sort + coalesced writeout (R5); block count = latency
//   hiding for random gathers -> pull agg with 25K blocks (R7); register-
//   held data beats LDS staging (R9); bucket totals derived from run table
//   (R10, -100us).
// R11: (a) gemm was LDS-issue bound (128 ds_read/node): W column held in
//   64 VGPRs, X row loaded coalesced + readlane broadcast -> no LDS in the
//   hot loop. (b) bfin3 stage-in was a serial dependent-load chain
//   (thread-per-run): LDS address-expansion then 20 independent unrolled
//   gathers per thread (full MLP). Everything else identical to R10.

#define NPB   128
#define BSH   7
#define BMSK  127
#define MAXB  1024          // >= B = ceil(100000/128) = 782
#define ROST  (MAXB + 1)    // runoff row stride
#define CHUNK 4096
#define EPTH  16            // edges per thread = CHUNK/256
#define MAXCH 1024          // >= nchunk = ceil(E/CHUNK) = 782
#define BCAP  5120          // bucket cap (mean 4096, sd 64 -> +16sd)
#define GPT   20            // gather regs per thread = BCAP/256

// Sort chunk k by dst-bucket; edge data held in REGISTERS between passes.
__global__ __launch_bounds__(256) void k_scatter(const int* __restrict__ src,
                                                 const int* __restrict__ dst,
                                                 int* __restrict__ runoff,
                                                 int* __restrict__ packed,
                                                 int E, int B) {
  __shared__ int sorted[CHUNK];
  __shared__ int hist[MAXB];
  __shared__ int wsum[4];
  int t = threadIdx.x;
  int k = blockIdx.x;
  int e0 = k * CHUNK;
  int cnt = min(CHUNK, E - e0);
  for (int b = t; b < B; b += 256) hist[b] = 0;
  __syncthreads();
  int pk[EPTH];
  int bk[EPTH];
  int base = t * EPTH;
  int nloc = min(EPTH, max(0, cnt - base));
  if (cnt == CHUNK) {
    const int4* s4 = (const int4*)(src + e0 + base);
    const int4* d4 = (const int4*)(dst + e0 + base);
#pragma unroll
    for (int g = 0; g < 4; ++g) {
      int4 sv = s4[g];
      int4 dv = d4[g];
      pk[4 * g + 0] = (sv.x << BSH) | (dv.x & BMSK); bk[4 * g + 0] = dv.x >> BSH;
      pk[4 * g + 1] = (sv.y << BSH) | (dv.y & BMSK); bk[4 * g + 1] = dv.y >> BSH;
      pk[4 * g + 2] = (sv.z << BSH) | (dv.z & BMSK); bk[4 * g + 2] = dv.z >> BSH;
      pk[4 * g + 3] = (sv.w << BSH) | (dv.w & BMSK); bk[4 * g + 3] = dv.w >> BSH;
      atomicAdd(&hist[bk[4 * g + 0]], 1);
      atomicAdd(&hist[bk[4 * g + 1]], 1);
      atomicAdd(&hist[bk[4 * g + 2]], 1);
      atomicAdd(&hist[bk[4 * g + 3]], 1);
    }
  } else {
    for (int q = 0; q < nloc; ++q) {
      int d = dst[e0 + base + q], s = src[e0 + base + q];
      pk[q] = (s << BSH) | (d & BMSK);
      bk[q] = d >> BSH;
      atomicAdd(&hist[bk[q]], 1);
    }
  }
  __syncthreads();
  int i0 = t * 4;
  int v0 = (i0 + 0 < B) ? hist[i0 + 0] : 0;
  int v1 = (i0 + 1 < B) ? hist[i0 + 1] : 0;
  int v2 = (i0 + 2 < B) ? hist[i0 + 2] : 0;
  int v3 = (i0 + 3 < B) ? hist[i0 + 3] : 0;
  int tsum = v0 + v1 + v2 + v3;
  int lane = t & 63, wid = t >> 6;
  int x = tsum;
#pragma unroll
  for (int d = 1; d < 64; d <<= 1) {
    int y = __shfl_up(x, d, 64);
    if (lane >= d) x += y;
  }
  if (lane == 63) wsum[wid] = x;
  __syncthreads();
  int wofs = 0;
  for (int ww = 0; ww < wid; ++ww) wofs += wsum[ww];
  int excl = wofs + x - tsum;
  hist[i0 + 0] = excl;
  hist[i0 + 1] = excl + v0;
  hist[i0 + 2] = excl + v0 + v1;
  hist[i0 + 3] = excl + v0 + v1 + v2;
  __syncthreads();
  int* row = runoff + (size_t)k * ROST;
  for (int b = t; b < B; b += 256) row[b] = hist[b];
  if (t == 0) row[B] = cnt;
  __syncthreads();
#pragma unroll
  for (int q = 0; q < EPTH; ++q) {
    if (q < nloc) {
      int pos = atomicAdd(&hist[bk[q]], 1);
      sorted[pos] = pk[q];
    }
  }
  __syncthreads();
  if (cnt == CHUNK) {
    int4* po = (int4*)(packed + e0 + base);
    const int4* so = (const int4*)(sorted + base);
#pragma unroll
    for (int g = 0; g < 4; ++g) po[g] = so[g];
  } else {
    for (int i = t; i < cnt; i += 256) packed[e0 + i] = sorted[i];
  }
}

// Tiled transpose: AT[b][k] = A[k][b].
__global__ __launch_bounds__(256) void k_transpose(const int* __restrict__ A,
                                                   int* __restrict__ AT,
                                                   int rows, int cols) {
  __shared__ int tile[32][33];
  int bx = blockIdx.x * 32;
  int by = blockIdx.y * 32;
  int tx = threadIdx.x & 31, ty = threadIdx.x >> 5;
#pragma unroll
  for (int q = 0; q < 4; ++q) {
    int r = by + ty + q * 8, c = bx + tx;
    if (r < rows && c < cols) tile[ty + q * 8][tx] = A[(size_t)r * ROST + c];
  }
  __syncthreads();
#pragma unroll
  for (int q = 0; q < 4; ++q) {
    int c = bx + ty + q * 8;
    int r = by + tx;
    if (c < cols && r < rows) AT[(size_t)c * MAXCH + r] = tile[tx][ty + q * 8];
  }
}

// Per-bucket totals from the transposed run table. No atomics.
__global__ __launch_bounds__(256) void k_bsum(const int* __restrict__ runoffT,
                                              int* __restrict__ btot,
                                              int B, int nchunk) {
  int b = (blockIdx.x * blockDim.x + threadIdx.x) >> 6;
  int lane = threadIdx.x & 63;
  if (b >= B) return;
  const int* r0 = runoffT + (size_t)b * MAXCH;
  const int* r1 = runoffT + (size_t)(b + 1) * MAXCH;
  int s = 0;
  for (int k = lane; k < nchunk; k += 64) s += r1[k] - r0[k];
#pragma unroll
  for (int d = 32; d >= 1; d >>= 1) s += __shfl_down(s, d, 64);
  if (lane == 0) btot[b] = s;
}

// Exclusive scan of bucket totals -> bbase[0..B], bbase[B]=E. One block.
__global__ __launch_bounds__(1024) void k_btot(const int* __restrict__ btot,
                                               int* __restrict__ bbase,
                                               int B, int E) {
  __shared__ int wsum[16];
  int t = threadIdx.x;
  int c = (t < B) ? btot[t] : 0;
  int lane = t & 63, wid = t >> 6;
  int x = c;
#pragma unroll
  for (int d = 1; d < 64; d <<= 1) {
    int y = __shfl_up(x, d, 64);
    if (lane >= d) x += y;
  }
  if (lane == 63) wsum[wid] = x;
  __syncthreads();
  int wofs = 0;
  for (int ww = 0; ww < wid; ++ww) wofs += wsum[ww];
  if (t < B) bbase[t] = wofs + x - c;
  if (t == 0) bbase[B] = E;
}

// Per-bucket finalize: run table -> scan -> LDS addr-expansion -> 20-deep
// MLP gather -> count -> scan -> node-scatter -> coalesced csr writeout.
__global__ __launch_bounds__(256) void k_bfin4(const int* __restrict__ packed,
                                               const int* __restrict__ runoffT,
                                               const int* __restrict__ bbase,
                                               int* __restrict__ off,
                                               float* __restrict__ dinv,
                                               int* __restrict__ csr,
                                               int N, int B, int nchunk) {
  __shared__ int rs[MAXCH];
  __shared__ unsigned short rl[MAXCH];
  __shared__ int pref[MAXCH];
  __shared__ int stage[BCAP];
  __shared__ int slot[BCAP];   // phase A: gather addresses; phase B: sorted out
  __shared__ int cntL[NPB];
  __shared__ int curL[NPB];
  __shared__ int wsum[4];
  int t = threadIdx.x;
  int b = blockIdx.x;
  for (int k = t; k < nchunk; k += 256) {
    int s = runoffT[(size_t)b * MAXCH + k];
    int e = runoffT[(size_t)(b + 1) * MAXCH + k];
    rs[k] = k * CHUNK + s;
    rl[k] = (unsigned short)(e - s);
  }
  if (t < NPB) cntL[t] = 0;
  __syncthreads();
  // scan run lengths -> pref
  int i0 = t * 4;
  int v0 = (i0 + 0 < nchunk) ? rl[i0 + 0] : 0;
  int v1 = (i0 + 1 < nchunk) ? rl[i0 + 1] : 0;
  int v2 = (i0 + 2 < nchunk) ? rl[i0 + 2] : 0;
  int v3 = (i0 + 3 < nchunk) ? rl[i0 + 3] : 0;
  int tsum = v0 + v1 + v2 + v3;
  int lane = t & 63, w = t >> 6;
  int x = tsum;
#pragma unroll
  for (int d = 1; d < 64; d <<= 1) {
    int y = __shfl_up(x, d, 64);
    if (lane >= d) x += y;
  }
  if (lane == 63) wsum[w] = x;
  __syncthreads();
  int wofs = 0;
  for (int ww = 0; ww < w; ++ww) wofs += wsum[ww];
  int excl = wofs + x - tsum;
  pref[i0 + 0] = excl;
  pref[i0 + 1] = excl + v0;
  pref[i0 + 2] = excl + v0 + v1;
  pref[i0 + 3] = excl + v0 + v1 + v2;
  __syncthreads();
  int wbase = bbase[b];
  int total = bbase[b + 1] - wbase;
  bool inLDS = (total <= BCAP);
  if (inLDS) {
    // phase 1: expand runs -> per-slot gather addresses (LDS writes only)
    for (int k = t; k < nchunk; k += 256) {
      int base = rs[k], len = rl[k], o = pref[k];
      for (int j = 0; j < len; ++j) slot[o + j] = base + j;
    }
    __syncthreads();
    // phase 2: 20 independent gathers per thread (full MLP), then count
    int av[GPT], ev[GPT];
#pragma unroll
    for (int g = 0; g < GPT; ++g) {
      int i = t + g * 256;
      av[g] = (i < total) ? slot[i] : -1;
    }
#pragma unroll
    for (int g = 0; g < GPT; ++g) ev[g] = (av[g] >= 0) ? packed[av[g]] : 0;
#pragma unroll
    for (int g = 0; g < GPT; ++g) {
      int i = t + g * 256;
      if (i < total) {
        stage[i] = ev[g];
        atomicAdd(&cntL[ev[g] & BMSK], 1);
      }
    }
  } else {
    for (int k = t; k < nchunk; k += 256) {
      int base = rs[k], len = rl[k];
      for (int j = 0; j < len; ++j)
        atomicAdd(&cntL[packed[base + j] & BMSK], 1);
    }
  }
  __syncthreads();
  // scan node counts -> off/dinv/cursors
  int c = (t < NPB) ? cntL[t] : 0;
  x = c;
#pragma unroll
  for (int d = 1; d < 64; d <<= 1) {
    int y = __shfl_up(x, d, 64);
    if (lane >= d) x += y;
  }
  if (lane == 63) wsum[w] = x;
  __syncthreads();
  wofs = 0;
  for (int ww = 0; ww < w; ++ww) wofs += wsum[ww];
  int nexcl = wofs + x - c;
  int v = (b << BSH) + t;
  if (t < NPB && v < N) {
    off[v] = wbase + nexcl;
    dinv[v] = rsqrtf((float)(c + 1));  // +1 self-loop
  }
  if (t < NPB) curL[t] = inLDS ? nexcl : (wbase + nexcl);
  if (b == B - 1 && t == 0) off[N] = bbase[B];
  __syncthreads();
  if (inLDS) {
    for (int i = t; i < total; i += 256) {
      int e = stage[i];
      int p = atomicAdd(&curL[e & BMSK], 1);
      slot[p] = e >> BSH;   // slot reused as sorted output
    }
    __syncthreads();
    for (int i = t; i < total; i += 256) csr[wbase + i] = slot[i];
  } else {
    for (int k = t; k < nchunk; k += 256) {
      int base = rs[k], len = rl[k];
      for (int j = 0; j < len; ++j) {
        int e = packed[base + j];
        int p = atomicAdd(&curL[e & BMSK], 1);
        csr[p] = e >> BSH;
      }
    }
  }
}

// H'[v] = fp16((X @ W)[v] * dinv[v]).  W column in 64 VGPRs; X row loaded
// coalesced (lane k holds x[v][k]) and broadcast via shfl. No LDS in loop.
__global__ __launch_bounds__(256) void k_gemm64r(const float* __restrict__ X,
                                                 const float* __restrict__ W,
                                                 const float* __restrict__ dinv,
                                                 __half* __restrict__ H, int N) {
  __shared__ float Wl[4096];
  for (int t = threadIdx.x; t < 4096; t += 256) Wl[t] = W[t];
  __syncthreads();
  int lane = threadIdx.x & 63;
  int w = threadIdx.x >> 6;
  float wc[64];
#pragma unroll
  for (int k = 0; k < 64; ++k) wc[k] = Wl[k * 64 + lane];
  int nwaves = gridDim.x * 4;
  for (int v = blockIdx.x * 4 + w; v < N; v += nwaves) {
    float xk = X[(size_t)v * 64 + lane];  // lane k holds x[v][k]
    float acc = 0.f;
#pragma unroll
    for (int k = 0; k < 64; ++k) {
      float xv = __shfl(xk, k, 64);
      acc = fmaf(xv, wc[k], acc);
    }
    H[(size_t)v * 64 + lane] = __float2half_rn(acc * dinv[v]);
  }
}

// Pull aggregation, dual-edge (benched R8 version, unchanged).
template <bool RELU>
__global__ __launch_bounds__(256) void k_agg(const __half* __restrict__ H,
                                             const int* __restrict__ csr,
                                             const int* __restrict__ off,
                                             const float* __restrict__ dinv,
                                             const float* __restrict__ bias,
                                             float* __restrict__ out, int N) {
  int wid = (blockIdx.x * blockDim.x + threadIdx.x) >> 6;
  int lane = threadIdx.x & 63;
  if (wid >= N) return;
  int hl = lane & 31;
  int half = lane >> 5;
  int beg = off[wid];
  int num = off[wid + 1] - beg;
  const __half2* Hp = (const __half2*)H;
  float2 fs = __half22float2(Hp[(size_t)wid * 32 + hl]);
  float2 acc = half ? make_float2(0.f, 0.f) : fs;
  for (int base = 0; base < num; base += 64) {
    int navail = min(64, num - base);
    int sv = (base + lane < num) ? csr[beg + base + lane] : 0;
    int npair = navail >> 1;
    int i = 0;
    for (; i + 8 <= npair; i += 8) {
      int e0 = __shfl(sv, 2 * (i + 0) + half), e1 = __shfl(sv, 2 * (i + 1) + half);
      int e2 = __shfl(sv, 2 * (i + 2) + half), e3 = __shfl(sv, 2 * (i + 3) + half);
      int e4 = __shfl(sv, 2 * (i + 4) + half), e5 = __shfl(sv, 2 * (i + 5) + half);
      int e6 = __shfl(sv, 2 * (i + 6) + half), e7 = __shfl(sv, 2 * (i + 7) + half);
      float2 f0 = __half22float2(Hp[(size_t)e0 * 32 + hl]);
      float2 f1 = __half22float2(Hp[(size_t)e1 * 32 + hl]);
      float2 f2 = __half22float2(Hp[(size_t)e2 * 32 + hl]);
      float2 f3 = __half22float2(Hp[(size_t)e3 * 32 + hl]);
      float2 f4 = __half22float2(Hp[(size_t)e4 * 32 + hl]);
      float2 f5 = __half22float2(Hp[(size_t)e5 * 32 + hl]);
      float2 f6 = __half22float2(Hp[(size_t)e6 * 32 + hl]);
      float2 f7 = __half22float2(Hp[(size_t)e7 * 32 + hl]);
      acc.x += f0.x + f1.x + f2.x + f3.x;
      acc.y += f0.y + f1.y + f2.y + f3.y;
      acc.x += f4.x + f5.x + f6.x + f7.x;
      acc.y += f4.y + f5.y + f6.y + f7.y;
    }
    for (; i < npair; ++i) {
      int e = __shfl(sv, 2 * i + half);
      float2 f = __half22float2(Hp[(size_t)e * 32 + hl]);
      acc.x += f.x; acc.y += f.y;
    }
    if (navail & 1) {
      int e = __shfl(sv, navail - 1);
      if (!half) {
        float2 f = __half22float2(Hp[(size_t)e * 32 + hl]);
        acc.x += f.x; acc.y += f.y;
      }
    }
  }
  acc.x += __shfl_xor(acc.x, 32);
  acc.y += __shfl_xor(acc.y, 32);
  if (!half) {
    float dv = dinv[wid];
    float2 bb = ((const float2*)bias)[hl];
    float2 r;
    r.x = fmaf(acc.x, dv, bb.x);
    r.y = fmaf(acc.y, dv, bb.y);
    if (RELU) { r.x = fmaxf(r.x, 0.f); r.y = fmaxf(r.y, 0.f); }
    ((float2*)(out + (size_t)wid * 64))[hl] = r;
  }
}

extern "C" void kernel_launch(void* const* d_in, const int* in_sizes, int n_in,
                              void* d_out, int out_size, void* d_ws, size_t ws_size,
                              hipStream_t stream) {
  const float* x  = (const float*)d_in[0];
  const float* W1 = (const float*)d_in[1];
  const float* b1 = (const float*)d_in[2];
  const float* W2 = (const float*)d_in[3];
  const float* b2 = (const float*)d_in[4];
  const int*   e0 = (const int*)d_in[5];
  const int*   e1 = (const int*)d_in[6];
  float* out = (float*)d_out;

  const int N = in_sizes[0] / 64;      // 100000
  const int E = in_sizes[5] / 2;       // 3200000
  const int B = (N + NPB - 1) / NPB;   // 782
  const int nchunk = (E + CHUNK - 1) / CHUNK;  // 782
  const int* src0 = e0;     const int* dst0 = e0 + E;
  const int* src1 = e1;     const int* dst1 = e1 + E;

  char* w = (char*)d_ws;
  size_t o = 0;
  auto carve = [&](size_t bytes) -> void* {
    void* p = w + o;
    o = (o + bytes + 255) & ~(size_t)255;
    return p;
  };
  int* btot = (int*)carve((size_t)MAXB * 4);
  int* bbase = (int*)carve((MAXB + 1) * 4);
  int* runoff = (int*)carve((size_t)MAXCH * ROST * 4);        // shared
  int* runoffT = (int*)carve((size_t)(MAXB + 1) * MAXCH * 4); // shared
  int* off = (int*)carve((size_t)(N + 1) * 4);     // shared (serialized)
  float* dinv = (float*)carve((size_t)N * 4);      // shared (serialized)
  int* packed = (int*)carve((size_t)nchunk * CHUNK * 4);  // shared
  int* csr = (int*)carve((size_t)E * 4);           // shared (serialized)
  __half* H = (__half*)carve((size_t)N * 64 * 2);

  const int aggblk = (N * 64 + 255) / 256;  // 25000
  const int bsumblk = (B * 64 + 255) / 256; // 196
  const dim3 tgrid((B + 1 + 31) / 32, (nchunk + 31) / 32);

  // layer 1
  k_scatter<<<nchunk, 256, 0, stream>>>(src0, dst0, runoff, packed, E, B);
  k_transpose<<<tgrid, 256, 0, stream>>>(runoff, runoffT, nchunk, B + 1);
  k_bsum<<<bsumblk, 256, 0, stream>>>(runoffT, btot, B, nchunk);
  k_btot<<<1, 1024, 0, stream>>>(btot, bbase, B, E);
  k_bfin4<<<B, 256, 0, stream>>>(packed, runoffT, bbase, off, dinv, csr, N, B, nchunk);
  k_gemm64r<<<2048, 256, 0, stream>>>(x, W1, dinv, H, N);
  k_agg<true><<<aggblk, 256, 0, stream>>>(H, csr, off, dinv, b1, out, N);

  // layer 2 (all scratch reused; stream order serializes)
  k_scatter<<<nchunk, 256, 0, stream>>>(src1, dst1, runoff, packed, E, B);
  k_transpose<<<tgrid, 256, 0, stream>>>(runoff, runoffT, nchunk, B + 1);
  k_bsum<<<bsumblk, 256, 0, stream>>>(runoffT, btot, B, nchunk);
  k_btot<<<1, 1024, 0, stream>>>(btot, bbase, B, E);
  k_bfin4<<<B, 256, 0, stream>>>(packed, runoffT, bbase, off, dinv, csr, N, B, nchunk);
  k_gemm64r<<<2048, 256, 0, stream>>>(out, W2, dinv, H, N);
  k_agg<false><<<aggblk, 256, 0, stream>>>(H, csr, off, dinv, b2, out, N);
}

// Round 12
// 359.712 us; speedup vs baseline: 1.3097x; 1.3097x over previous
//
#include <hip/hip_runtime.h>
#include <hip/hip_fp16.h>

// 2-layer GCN: out = gcn(relu(gcn(x,W1,b1,e0)), W2, b2, e1)
// Lessons: no device-scope atomics (R2/R10); write-amp 1.0 via LDS chunk
//   sort + coalesced writeout (R5); block count = latency hiding for
//   random gathers -> pull agg, 25K blocks (R7); registers beat LDS for
//   pass-to-pass data (R9); bucket totals from run table (R10).
// R11 post-mortem: shfl-broadcast gemm REGRESSED (84us): __shfl is a DS op
//   (ds_bpermute) -> 64 DS ops + 64-deep serial fma chain per node.
// R12: register-tile gemm: thread = 4 nodes x 4 features; X tile staged
//   TRANSPOSED (Xt[k][n], conflict-free); inner k: 2x ds_read_b128 + 16
//   independent fma -> VALU-bound (~6us) not DS/issue-bound.

#define NPB   128
#define BSH   7
#define BMSK  127
#define MAXB  1024          // >= B = ceil(100000/128) = 782
#define ROST  (MAXB + 1)    // runoff row stride
#define CHUNK 4096
#define EPTH  16            // edges per thread = CHUNK/256
#define MAXCH 1024          // >= nchunk = ceil(E/CHUNK) = 782
#define BCAP  5120          // bucket cap (mean 4096, sd 64 -> +16sd)
#define GPT   20            // gather regs per thread = BCAP/256

// Sort chunk k by dst-bucket; edge data held in REGISTERS between passes.
__global__ __launch_bounds__(256) void k_scatter(const int* __restrict__ src,
                                                 const int* __restrict__ dst,
                                                 int* __restrict__ runoff,
                                                 int* __restrict__ packed,
                                                 int E, int B) {
  __shared__ int sorted[CHUNK];
  __shared__ int hist[MAXB];
  __shared__ int wsum[4];
  int t = threadIdx.x;
  int k = blockIdx.x;
  int e0 = k * CHUNK;
  int cnt = min(CHUNK, E - e0);
  for (int b = t; b < B; b += 256) hist[b] = 0;
  __syncthreads();
  int pk[EPTH];
  int bk[EPTH];
  int base = t * EPTH;
  int nloc = min(EPTH, max(0, cnt - base));
  if (cnt == CHUNK) {
    const int4* s4 = (const int4*)(src + e0 + base);
    const int4* d4 = (const int4*)(dst + e0 + base);
#pragma unroll
    for (int g = 0; g < 4; ++g) {
      int4 sv = s4[g];
      int4 dv = d4[g];
      pk[4 * g + 0] = (sv.x << BSH) | (dv.x & BMSK); bk[4 * g + 0] = dv.x >> BSH;
      pk[4 * g + 1] = (sv.y << BSH) | (dv.y & BMSK); bk[4 * g + 1] = dv.y >> BSH;
      pk[4 * g + 2] = (sv.z << BSH) | (dv.z & BMSK); bk[4 * g + 2] = dv.z >> BSH;
      pk[4 * g + 3] = (sv.w << BSH) | (dv.w & BMSK); bk[4 * g + 3] = dv.w >> BSH;
      atomicAdd(&hist[bk[4 * g + 0]], 1);
      atomicAdd(&hist[bk[4 * g + 1]], 1);
      atomicAdd(&hist[bk[4 * g + 2]], 1);
      atomicAdd(&hist[bk[4 * g + 3]], 1);
    }
  } else {
    for (int q = 0; q < nloc; ++q) {
      int d = dst[e0 + base + q], s = src[e0 + base + q];
      pk[q] = (s << BSH) | (d & BMSK);
      bk[q] = d >> BSH;
      atomicAdd(&hist[bk[q]], 1);
    }
  }
  __syncthreads();
  int i0 = t * 4;
  int v0 = (i0 + 0 < B) ? hist[i0 + 0] : 0;
  int v1 = (i0 + 1 < B) ? hist[i0 + 1] : 0;
  int v2 = (i0 + 2 < B) ? hist[i0 + 2] : 0;
  int v3 = (i0 + 3 < B) ? hist[i0 + 3] : 0;
  int tsum = v0 + v1 + v2 + v3;
  int lane = t & 63, wid = t >> 6;
  int x = tsum;
#pragma unroll
  for (int d = 1; d < 64; d <<= 1) {
    int y = __shfl_up(x, d, 64);
    if (lane >= d) x += y;
  }
  if (lane == 63) wsum[wid] = x;
  __syncthreads();
  int wofs = 0;
  for (int ww = 0; ww < wid; ++ww) wofs += wsum[ww];
  int excl = wofs + x - tsum;
  hist[i0 + 0] = excl;
  hist[i0 + 1] = excl + v0;
  hist[i0 + 2] = excl + v0 + v1;
  hist[i0 + 3] = excl + v0 + v1 + v2;
  __syncthreads();
  int* row = runoff + (size_t)k * ROST;
  for (int b = t; b < B; b += 256) row[b] = hist[b];
  if (t == 0) row[B] = cnt;
  __syncthreads();
#pragma unroll
  for (int q = 0; q < EPTH; ++q) {
    if (q < nloc) {
      int pos = atomicAdd(&hist[bk[q]], 1);
      sorted[pos] = pk[q];
    }
  }
  __syncthreads();
  if (cnt == CHUNK) {
    int4* po = (int4*)(packed + e0 + base);
    const int4* so = (const int4*)(sorted + base);
#pragma unroll
    for (int g = 0; g < 4; ++g) po[g] = so[g];
  } else {
    for (int i = t; i < cnt; i += 256) packed[e0 + i] = sorted[i];
  }
}

// Tiled transpose: AT[b][k] = A[k][b].
__global__ __launch_bounds__(256) void k_transpose(const int* __restrict__ A,
                                                   int* __restrict__ AT,
                                                   int rows, int cols) {
  __shared__ int tile[32][33];
  int bx = blockIdx.x * 32;
  int by = blockIdx.y * 32;
  int tx = threadIdx.x & 31, ty = threadIdx.x >> 5;
#pragma unroll
  for (int q = 0; q < 4; ++q) {
    int r = by + ty + q * 8, c = bx + tx;
    if (r < rows && c < cols) tile[ty + q * 8][tx] = A[(size_t)r * ROST + c];
  }
  __syncthreads();
#pragma unroll
  for (int q = 0; q < 4; ++q) {
    int c = bx + ty + q * 8;
    int r = by + tx;
    if (c < cols && r < rows) AT[(size_t)c * MAXCH + r] = tile[tx][ty + q * 8];
  }
}

// Per-bucket totals from the transposed run table. No atomics.
__global__ __launch_bounds__(256) void k_bsum(const int* __restrict__ runoffT,
                                              int* __restrict__ btot,
                                              int B, int nchunk) {
  int b = (blockIdx.x * blockDim.x + threadIdx.x) >> 6;
  int lane = threadIdx.x & 63;
  if (b >= B) return;
  const int* r0 = runoffT + (size_t)b * MAXCH;
  const int* r1 = runoffT + (size_t)(b + 1) * MAXCH;
  int s = 0;
  for (int k = lane; k < nchunk; k += 64) s += r1[k] - r0[k];
#pragma unroll
  for (int d = 32; d >= 1; d >>= 1) s += __shfl_down(s, d, 64);
  if (lane == 0) btot[b] = s;
}

// Exclusive scan of bucket totals -> bbase[0..B], bbase[B]=E. One block.
__global__ __launch_bounds__(1024) void k_btot(const int* __restrict__ btot,
                                               int* __restrict__ bbase,
                                               int B, int E) {
  __shared__ int wsum[16];
  int t = threadIdx.x;
  int c = (t < B) ? btot[t] : 0;
  int lane = t & 63, wid = t >> 6;
  int x = c;
#pragma unroll
  for (int d = 1; d < 64; d <<= 1) {
    int y = __shfl_up(x, d, 64);
    if (lane >= d) x += y;
  }
  if (lane == 63) wsum[wid] = x;
  __syncthreads();
  int wofs = 0;
  for (int ww = 0; ww < wid; ++ww) wofs += wsum[ww];
  if (t < B) bbase[t] = wofs + x - c;
  if (t == 0) bbase[B] = E;
}

// Per-bucket finalize (R11 version): addr-expansion + 20-deep MLP gather.
__global__ __launch_bounds__(256) void k_bfin4(const int* __restrict__ packed,
                                               const int* __restrict__ runoffT,
                                               const int* __restrict__ bbase,
                                               int* __restrict__ off,
                                               float* __restrict__ dinv,
                                               int* __restrict__ csr,
                                               int N, int B, int nchunk) {
  __shared__ int rs[MAXCH];
  __shared__ unsigned short rl[MAXCH];
  __shared__ int pref[MAXCH];
  __shared__ int stage[BCAP];
  __shared__ int slot[BCAP];
  __shared__ int cntL[NPB];
  __shared__ int curL[NPB];
  __shared__ int wsum[4];
  int t = threadIdx.x;
  int b = blockIdx.x;
  for (int k = t; k < nchunk; k += 256) {
    int s = runoffT[(size_t)b * MAXCH + k];
    int e = runoffT[(size_t)(b + 1) * MAXCH + k];
    rs[k] = k * CHUNK + s;
    rl[k] = (unsigned short)(e - s);
  }
  if (t < NPB) cntL[t] = 0;
  __syncthreads();
  int i0 = t * 4;
  int v0 = (i0 + 0 < nchunk) ? rl[i0 + 0] : 0;
  int v1 = (i0 + 1 < nchunk) ? rl[i0 + 1] : 0;
  int v2 = (i0 + 2 < nchunk) ? rl[i0 + 2] : 0;
  int v3 = (i0 + 3 < nchunk) ? rl[i0 + 3] : 0;
  int tsum = v0 + v1 + v2 + v3;
  int lane = t & 63, w = t >> 6;
  int x = tsum;
#pragma unroll
  for (int d = 1; d < 64; d <<= 1) {
    int y = __shfl_up(x, d, 64);
    if (lane >= d) x += y;
  }
  if (lane == 63) wsum[w] = x;
  __syncthreads();
  int wofs = 0;
  for (int ww = 0; ww < w; ++ww) wofs += wsum[ww];
  int excl = wofs + x - tsum;
  pref[i0 + 0] = excl;
  pref[i0 + 1] = excl + v0;
  pref[i0 + 2] = excl + v0 + v1;
  pref[i0 + 3] = excl + v0 + v1 + v2;
  __syncthreads();
  int wbase = bbase[b];
  int total = bbase[b + 1] - wbase;
  bool inLDS = (total <= BCAP);
  if (inLDS) {
    for (int k = t; k < nchunk; k += 256) {
      int base = rs[k], len = rl[k], o = pref[k];
      for (int j = 0; j < len; ++j) slot[o + j] = base + j;
    }
    __syncthreads();
    int av[GPT], ev[GPT];
#pragma unroll
    for (int g = 0; g < GPT; ++g) {
      int i = t + g * 256;
      av[g] = (i < total) ? slot[i] : -1;
    }
#pragma unroll
    for (int g = 0; g < GPT; ++g) ev[g] = (av[g] >= 0) ? packed[av[g]] : 0;
#pragma unroll
    for (int g = 0; g < GPT; ++g) {
      int i = t + g * 256;
      if (i < total) {
        stage[i] = ev[g];
        atomicAdd(&cntL[ev[g] & BMSK], 1);
      }
    }
  } else {
    for (int k = t; k < nchunk; k += 256) {
      int base = rs[k], len = rl[k];
      for (int j = 0; j < len; ++j)
        atomicAdd(&cntL[packed[base + j] & BMSK], 1);
    }
  }
  __syncthreads();
  int c = (t < NPB) ? cntL[t] : 0;
  x = c;
#pragma unroll
  for (int d = 1; d < 64; d <<= 1) {
    int y = __shfl_up(x, d, 64);
    if (lane >= d) x += y;
  }
  if (lane == 63) wsum[w] = x;
  __syncthreads();
  wofs = 0;
  for (int ww = 0; ww < w; ++ww) wofs += wsum[ww];
  int nexcl = wofs + x - c;
  int v = (b << BSH) + t;
  if (t < NPB && v < N) {
    off[v] = wbase + nexcl;
    dinv[v] = rsqrtf((float)(c + 1));  // +1 self-loop
  }
  if (t < NPB) curL[t] = inLDS ? nexcl : (wbase + nexcl);
  if (b == B - 1 && t == 0) off[N] = bbase[B];
  __syncthreads();
  if (inLDS) {
    for (int i = t; i < total; i += 256) {
      int e = stage[i];
      int p = atomicAdd(&curL[e & BMSK], 1);
      slot[p] = e >> BSH;
    }
    __syncthreads();
    for (int i = t; i < total; i += 256) csr[wbase + i] = slot[i];
  } else {
    for (int k = t; k < nchunk; k += 256) {
      int base = rs[k], len = rl[k];
      for (int j = 0; j < len; ++j) {
        int e = packed[base + j];
        int p = atomicAdd(&curL[e & BMSK], 1);
        csr[p] = e >> BSH;
      }
    }
  }
}

// H'[v] = fp16((X @ W)[v] * dinv[v]).  Register-tile GEMM: block = 64
// nodes x 64 features; thread = 4x4 tile. X staged transposed Xt[k][n]
// (bank-conflict-free); inner k: 2x ds_read_b128 + 16 independent fma.
__global__ __launch_bounds__(256) void k_gemm64t(const float* __restrict__ X,
                                                 const float* __restrict__ W,
                                                 const float* __restrict__ dinv,
                                                 __half* __restrict__ H, int N) {
  __shared__ float Wl[4096];   // [k][f]
  __shared__ float Xt[4096];   // [k][n] transposed tile
  int t = threadIdx.x;
  for (int i = t; i < 4096; i += 256) Wl[i] = W[i];
  int f0 = (t & 15) * 4;       // 4 features
  int ng = t >> 4;             // node group 0..15 -> nodes 4*ng..+3
  int sv = t & 63;             // staging: node within tile
  int sq = t >> 6;             // staging: k-quad -> k in [16*sq, 16*sq+16)
  int v0 = blockIdx.x * 64;
  // stage X tile transposed (coalesced float4 reads, stride-1 LDS writes)
  bool valid = (v0 + sv) < N;
  const float4* Xr = (const float4*)(X + (size_t)(v0 + sv) * 64 + sq * 16);
  int kb = sq * 16;
#pragma unroll
  for (int c = 0; c < 4; ++c) {
    float4 xv = valid ? Xr[c] : make_float4(0.f, 0.f, 0.f, 0.f);
    Xt[(kb + 4 * c + 0) * 64 + sv] = xv.x;
    Xt[(kb + 4 * c + 1) * 64 + sv] = xv.y;
    Xt[(kb + 4 * c + 2) * 64 + sv] = xv.z;
    Xt[(kb + 4 * c + 3) * 64 + sv] = xv.w;
  }
  __syncthreads();
  float acc[4][4] = {};
#pragma unroll 16
  for (int k = 0; k < 64; ++k) {
    float4 wv = *(const float4*)&Wl[k * 64 + f0];
    float4 xv = *(const float4*)&Xt[k * 64 + 4 * ng];
    acc[0][0] = fmaf(xv.x, wv.x, acc[0][0]);
    acc[0][1] = fmaf(xv.x, wv.y, acc[0][1]);
    acc[0][2] = fmaf(xv.x, wv.z, acc[0][2]);
    acc[0][3] = fmaf(xv.x, wv.w, acc[0][3]);
    acc[1][0] = fmaf(xv.y, wv.x, acc[1][0]);
    acc[1][1] = fmaf(xv.y, wv.y, acc[1][1]);
    acc[1][2] = fmaf(xv.y, wv.z, acc[1][2]);
    acc[1][3] = fmaf(xv.y, wv.w, acc[1][3]);
    acc[2][0] = fmaf(xv.z, wv.x, acc[2][0]);
    acc[2][1] = fmaf(xv.z, wv.y, acc[2][1]);
    acc[2][2] = fmaf(xv.z, wv.z, acc[2][2]);
    acc[2][3] = fmaf(xv.z, wv.w, acc[2][3]);
    acc[3][0] = fmaf(xv.w, wv.x, acc[3][0]);
    acc[3][1] = fmaf(xv.w, wv.y, acc[3][1]);
    acc[3][2] = fmaf(xv.w, wv.z, acc[3][2]);
    acc[3][3] = fmaf(xv.w, wv.w, acc[3][3]);
  }
#pragma unroll
  for (int i = 0; i < 4; ++i) {
    int v = v0 + 4 * ng + i;
    if (v < N) {
      float dv = dinv[v];
      __half2 h01 = __floats2half2_rn(acc[i][0] * dv, acc[i][1] * dv);
      __half2 h23 = __floats2half2_rn(acc[i][2] * dv, acc[i][3] * dv);
      __half2* dst = (__half2*)(H + (size_t)v * 64 + f0);
      dst[0] = h01;
      dst[1] = h23;
    }
  }
}

// Pull aggregation, dual-edge (benched R8 version, unchanged).
template <bool RELU>
__global__ __launch_bounds__(256) void k_agg(const __half* __restrict__ H,
                                             const int* __restrict__ csr,
                                             const int* __restrict__ off,
                                             const float* __restrict__ dinv,
                                             const float* __restrict__ bias,
                                             float* __restrict__ out, int N) {
  int wid = (blockIdx.x * blockDim.x + threadIdx.x) >> 6;
  int lane = threadIdx.x & 63;
  if (wid >= N) return;
  int hl = lane & 31;
  int half = lane >> 5;
  int beg = off[wid];
  int num = off[wid + 1] - beg;
  const __half2* Hp = (const __half2*)H;
  float2 fs = __half22float2(Hp[(size_t)wid * 32 + hl]);
  float2 acc = half ? make_float2(0.f, 0.f) : fs;
  for (int base = 0; base < num; base += 64) {
    int navail = min(64, num - base);
    int sv = (base + lane < num) ? csr[beg + base + lane] : 0;
    int npair = navail >> 1;
    int i = 0;
    for (; i + 8 <= npair; i += 8) {
      int e0 = __shfl(sv, 2 * (i + 0) + half), e1 = __shfl(sv, 2 * (i + 1) + half);
      int e2 = __shfl(sv, 2 * (i + 2) + half), e3 = __shfl(sv, 2 * (i + 3) + half);
      int e4 = __shfl(sv, 2 * (i + 4) + half), e5 = __shfl(sv, 2 * (i + 5) + half);
      int e6 = __shfl(sv, 2 * (i + 6) + half), e7 = __shfl(sv, 2 * (i + 7) + half);
      float2 f0 = __half22float2(Hp[(size_t)e0 * 32 + hl]);
      float2 f1 = __half22float2(Hp[(size_t)e1 * 32 + hl]);
      float2 f2 = __half22float2(Hp[(size_t)e2 * 32 + hl]);
      float2 f3 = __half22float2(Hp[(size_t)e3 * 32 + hl]);
      float2 f4 = __half22float2(Hp[(size_t)e4 * 32 + hl]);
      float2 f5 = __half22float2(Hp[(size_t)e5 * 32 + hl]);
      float2 f6 = __half22float2(Hp[(size_t)e6 * 32 + hl]);
      float2 f7 = __half22float2(Hp[(size_t)e7 * 32 + hl]);
      acc.x += f0.x + f1.x + f2.x + f3.x;
      acc.y += f0.y + f1.y + f2.y + f3.y;
      acc.x += f4.x + f5.x + f6.x + f7.x;
      acc.y += f4.y + f5.y + f6.y + f7.y;
    }
    for (; i < npair; ++i) {
      int e = __shfl(sv, 2 * i + half);
      float2 f = __half22float2(Hp[(size_t)e * 32 + hl]);
      acc.x += f.x; acc.y += f.y;
    }
    if (navail & 1) {
      int e = __shfl(sv, navail - 1);
      if (!half) {
        float2 f = __half22float2(Hp[(size_t)e * 32 + hl]);
        acc.x += f.x; acc.y += f.y;
      }
    }
  }
  acc.x += __shfl_xor(acc.x, 32);
  acc.y += __shfl_xor(acc.y, 32);
  if (!half) {
    float dv = dinv[wid];
    float2 bb = ((const float2*)bias)[hl];
    float2 r;
    r.x = fmaf(acc.x, dv, bb.x);
    r.y = fmaf(acc.y, dv, bb.y);
    if (RELU) { r.x = fmaxf(r.x, 0.f); r.y = fmaxf(r.y, 0.f); }
    ((float2*)(out + (size_t)wid * 64))[hl] = r;
  }
}

extern "C" void kernel_launch(void* const* d_in, const int* in_sizes, int n_in,
                              void* d_out, int out_size, void* d_ws, size_t ws_size,
                              hipStream_t stream) {
  const float* x  = (const float*)d_in[0];
  const float* W1 = (const float*)d_in[1];
  const float* b1 = (const float*)d_in[2];
  const float* W2 = (const float*)d_in[3];
  const float* b2 = (const float*)d_in[4];
  const int*   e0 = (const int*)d_in[5];
  const int*   e1 = (const int*)d_in[6];
  float* out = (float*)d_out;

  const int N = in_sizes[0] / 64;      // 100000
  const int E = in_sizes[5] / 2;       // 3200000
  const int B = (N + NPB - 1) / NPB;   // 782
  const int nchunk = (E + CHUNK - 1) / CHUNK;  // 782
  const int* src0 = e0;     const int* dst0 = e0 + E;
  const int* src1 = e1;     const int* dst1 = e1 + E;

  char* w = (char*)d_ws;
  size_t o = 0;
  auto carve = [&](size_t bytes) -> void* {
    void* p = w + o;
    o = (o + bytes + 255) & ~(size_t)255;
    return p;
  };
  int* btot = (int*)carve((size_t)MAXB * 4);
  int* bbase = (int*)carve((MAXB + 1) * 4);
  int* runoff = (int*)carve((size_t)MAXCH * ROST * 4);        // shared
  int* runoffT = (int*)carve((size_t)(MAXB + 1) * MAXCH * 4); // shared
  int* off = (int*)carve((size_t)(N + 1) * 4);     // shared (serialized)
  float* dinv = (float*)carve((size_t)N * 4);      // shared (serialized)
  int* packed = (int*)carve((size_t)nchunk * CHUNK * 4);  // shared
  int* csr = (int*)carve((size_t)E * 4);           // shared (serialized)
  __half* H = (__half*)carve((size_t)N * 64 * 2);

  const int aggblk = (N * 64 + 255) / 256;   // 25000
  const int bsumblk = (B * 64 + 255) / 256;  // 196
  const int gemmblk = (N + 63) / 64;         // 1563
  const dim3 tgrid((B + 1 + 31) / 32, (nchunk + 31) / 32);

  // layer 1
  k_scatter<<<nchunk, 256, 0, stream>>>(src0, dst0, runoff, packed, E, B);
  k_transpose<<<tgrid, 256, 0, stream>>>(runoff, runoffT, nchunk, B + 1);
  k_bsum<<<bsumblk, 256, 0, stream>>>(runoffT, btot, B, nchunk);
  k_btot<<<1, 1024, 0, stream>>>(btot, bbase, B, E);
  k_bfin4<<<B, 256, 0, stream>>>(packed, runoffT, bbase, off, dinv, csr, N, B, nchunk);
  k_gemm64t<<<gemmblk, 256, 0, stream>>>(x, W1, dinv, H, N);
  k_agg<true><<<aggblk, 256, 0, stream>>>(H, csr, off, dinv, b1, out, N);

  // layer 2 (all scratch reused; stream order serializes)
  k_scatter<<<nchunk, 256, 0, stream>>>(src1, dst1, runoff, packed, E, B);
  k_transpose<<<tgrid, 256, 0, stream>>>(runoff, runoffT, nchunk, B + 1);
  k_bsum<<<bsumblk, 256, 0, stream>>>(runoffT, btot, B, nchunk);
  k_btot<<<1, 1024, 0, stream>>>(btot, bbase, B, E);
  k_bfin4<<<B, 256, 0, stream>>>(packed, runoffT, bbase, off, dinv, csr, N, B, nchunk);
  k_gemm64t<<<gemmblk, 256, 0, stream>>>(out, W2, dinv, H, N);
  k_agg<false><<<aggblk, 256, 0, stream>>>(H, csr, off, dinv, b2, out, N);
}